// Round 8
// baseline (137.813 us; speedup 1.0000x reference)
//
#include <hip/hip_runtime.h>

// NCC loss, win=9, (1,1,160,192,224) fp32 -> scalar. Fully fused, round 16.
// Model (R9-R15): dur ~= VALU-cycles / busy-rate. R15 fixed balance (busy
// 40->60%) but grew VALU-cycles 56K->92K (duplicated load path: per-phase
// addr math + 24 OOB cndmasks x 128 extra threads) and added 806K bank
// conflicts (H-remap: hch pairs in one wave, SW_CS=576 == 0 mod 32).
// R16 = R15 with the load path made ~free + aliasing fixed:
//   - All load addressing hoisted to init: gh/gf0 bounds are STATIC per
//     thread; only z varies (block-uniform -> scalar). w_load = 1 scalar
//     clamp/mul + 6 saddr global_load_dwordx4 + 2 static edge selects.
//     OOB-z loads clamped (consumers guarded); OOB-row threads store zeros
//     in w_compute instead of zero-filling 24 regs per phase.
//   - SW_CS 576 -> 584 (16B-aligned, mod 32 = 8): H cross-channel reads
//     become <=2-way (free). W store pattern unchanged (measured 0-conflict).
// Structure identical to R15: single LDS-only barrier per slice;
//   bar; { F(j): SH[j&1] || H(j+1): SW[(j+1)&1]->SH[(j+1)&1]
//        || W(j+2): pf -> SW[j&1]; w_load(z+3) }
// W on all 256 threads (half0 ch {I,J,I*I}, half1 ch {J*J,I*J});
// H spread: wave w takes tasks w*40+lane (lane<40). DCH=28, 1008 blocks.

#define DD 160
#define HH 192
#define WW 224
#define W4 56                 // WW/4
#define SLICE (HH * WW)
#define S4 (SLICE / 4)
#define NVOX (DD * SLICE)
#define TW 32
#define TH 8
#define DCH 28                // grid.z = 6 -> 1008 blocks
#define ITERS (DCH + 8)       // 36 = 4 * 9 (phase-static ring)
#define NTHR 256
#define SW_RS 36              // row stride; b128-aligned, 0-conflict (R5/R7)
#define SW_CS 584             // channel stride: 16*36=576 +8 pad (mod 32 = 8)
#define SH_SZ (TH * TW * 5)   // 1280 floats
#define EPS 1e-5f
#define INV_WSUM (1.0f / 729.0f)

// Barrier that orders LDS only: s_waitcnt imm 0xC07F = lgkmcnt(0), vmcnt(63),
// expcnt(7) -> in-flight GLOBAL loads stay in flight across the barrier.
__device__ __forceinline__ void bar_lds_only() {
    __asm__ volatile("" ::: "memory");
    __builtin_amdgcn_s_waitcnt(0xC07F);
    __builtin_amdgcn_s_barrier();
    __asm__ volatile("" ::: "memory");
}

__global__ __launch_bounds__(NTHR, 4) void ncc_fused(const float* __restrict__ I,
                                                     const float* __restrict__ J,
                                                     float* __restrict__ out) {
    __shared__ float SW0[5 * SW_CS], SW1[5 * SW_CS];   // 11.68 KB each
    __shared__ float SH0[SH_SZ], SH1[SH_SZ];           // 5.12 KB each
    __shared__ float wred[NTHR / 64];

    const int tid = threadIdx.x;
    const int tx = tid & 31, ty = tid >> 5;    // F mapping: 32 x 8
    const int wlo = blockIdx.x * TW;
    const int hlo = blockIdx.y * TH;
    const int dlo = blockIdx.z * DCH;

    // W mapping: ALL threads; 2 threads per (row, f4-group), split by channel.
    const int half = tid >> 7;                 // 0: ch {I,J,I*I}  1: {J*J,I*J}
    const int rg   = tid & 127;
    const int wr = rg >> 3, wc = rg & 7;       // 16 rows x 8 groups
    const int gh = hlo - 4 + wr;
    const bool hok = (gh >= 0) && (gh < HH);
    const int gf0 = (wlo >> 2) - 1 + wc;

    // Static (per-thread, phase-invariant) load geometry. Middle f4 (gf0+1)
    // is provably always in [0, W4): gf0 in [-1, 54].
    const int gh_c  = gh < 0 ? 0 : (gh >= HH ? HH - 1 : gh);
    const bool f0ok = (gf0 >= 0);
    const bool f2ok = (gf0 + 2 < W4);
    const int f0c = f0ok ? gf0 : 0;
    const int f2c = f2ok ? gf0 + 2 : W4 - 1;
    const int o0 = (gh_c * W4 + f0c) * 16;     // byte offsets into a slice
    const int o1 = (gh_c * W4 + gf0 + 1) * 16;
    const int o2 = (gh_c * W4 + f2c) * 16;

    // H mapping: wave w takes tasks w*40 + lane (lane < 40); 160 tasks total.
    const int lane = tid & 63;
    const int htask = (tid >> 6) * 40 + lane;
    const bool hact = lane < 40;
    const int hcol = htask & 31, hch = htask >> 5;

    // prefetch registers: one slice-row of raw I/J (12 floats each)
    float pfa[12], pfb[12];

    auto w_load = [&](int z) {   // clamped loads; OOB consumers are guarded
        const int zc = z < 0 ? 0 : (z >= DD ? DD - 1 : z);
        const char* bI = (const char*)I + (size_t)zc * (SLICE * 4);
        const char* bJ = (const char*)J + (size_t)zc * (SLICE * 4);
        float4 a0 = *(const float4*)(bI + o0);
        float4 a1 = *(const float4*)(bI + o1);
        float4 a2 = *(const float4*)(bI + o2);
        float4 b0 = *(const float4*)(bJ + o0);
        float4 b1 = *(const float4*)(bJ + o1);
        float4 b2 = *(const float4*)(bJ + o2);
        if (!f0ok) { a0 = make_float4(0.f,0.f,0.f,0.f); b0 = make_float4(0.f,0.f,0.f,0.f); }
        if (!f2ok) { a2 = make_float4(0.f,0.f,0.f,0.f); b2 = make_float4(0.f,0.f,0.f,0.f); }
        pfa[0]=a0.x; pfa[1]=a0.y; pfa[2]=a0.z; pfa[3]=a0.w;
        pfa[4]=a1.x; pfa[5]=a1.y; pfa[6]=a1.z; pfa[7]=a1.w;
        pfa[8]=a2.x; pfa[9]=a2.y; pfa[10]=a2.z; pfa[11]=a2.w;
        pfb[0]=b0.x; pfb[1]=b0.y; pfb[2]=b0.z; pfb[3]=b0.w;
        pfb[4]=b1.x; pfb[5]=b1.y; pfb[6]=b1.z; pfb[7]=b1.w;
        pfb[8]=b2.x; pfb[9]=b2.y; pfb[10]=b2.z; pfb[11]=b2.w;
    };

    // slide 9-tap W-sums for this thread's 2-3 channels -> dst
    auto w_compute = [&](float* dst) {
        float* wp = dst + wr * SW_RS + 4 * wc;
        if (!hok) {                            // OOB row: box-sum must see 0
            const float4 zz = make_float4(0.f, 0.f, 0.f, 0.f);
            #pragma unroll
            for (int t = 0; t < 3; ++t) {
                if (half && t == 2) break;
                const int ch = half ? (3 + t) : t;
                *(float4*)(wp + ch * SW_CS) = zz;
            }
            return;
        }
        #pragma unroll
        for (int t = 0; t < 3; ++t) {
            if (half && t == 2) break;         // wave-uniform
            float v[12];
            #pragma unroll
            for (int k = 0; k < 12; ++k)
                v[k] = half ? ((t == 0) ? pfb[k] * pfb[k] : pfa[k] * pfb[k])
                            : ((t == 0) ? pfa[k]
                             : (t == 1) ? pfb[k]
                             :            pfa[k] * pfa[k]);
            float s = v[0];
            #pragma unroll
            for (int k = 1; k < 9; ++k) s += v[k];
            float4 o;
            o.x = s;
            s += v[9]  - v[0]; o.y = s;
            s += v[10] - v[1]; o.z = s;
            s += v[11] - v[2]; o.w = s;
            const int ch = half ? (3 + t) : t;
            *(float4*)(wp + ch * SW_CS) = o;   // b128, 16B-aligned
        }
    };

    auto h_phase = [&](const float* swSrc, float* shDst) {  // 9-tap H slide
        const float* p = swSrc + hch * SW_CS + hcol;
        float v[16];
        #pragma unroll
        for (int r = 0; r < 16; r += 2) {       // pairs -> ds_read2_b32
            const float* pr = p + r * SW_RS;
            v[r]     = pr[0];
            v[r + 1] = pr[SW_RS];
        }
        float s = v[0];
        #pragma unroll
        for (int r = 1; r < 9; ++r) s += v[r];
        float* o = shDst + hcol * 5 + hch;      // [row][col][ch]
        float prev = s;
        o[0] = s;
        #pragma unroll
        for (int r = 1; r < TH; ++r) {
            prev += v[r + 8] - v[r - 1];
            o[r * (TW * 5)] = prev;
        }
    };

    float q0[9], q1[9], q2[9], q3[9], q4[9];
    #pragma unroll
    for (int k = 0; k < 9; ++k) { q0[k]=0.f; q1[k]=0.f; q2[k]=0.f; q3[k]=0.f; q4[k]=0.f; }
    float r0=0.f, r1=0.f, r2=0.f, r3=0.f, r4=0.f;
    float acc = 0.f;

    // ---- prologue: W(0) -> SW0, prefetch slice 1 ----
    const int z0 = dlo - 4;
    w_load(z0);
    if (z0 >= 0) w_compute(SW0);        // z0 < DD always (dlo <= 140)
    w_load(z0 + 1);
    bar_lds_only();

    // ---- P0: H(0), W(1), prefetch slice 2 (no F yet) ----
    if (hact && z0 >= 0) h_phase(SW0, SH0);
    {
        const int z1 = z0 + 1;
        if (z1 >= 0 && z1 < DD) w_compute(SW1);
        w_load(z0 + 2);
    }

    // ---- main: 36 phases, ONE barrier each ----
    #pragma unroll 1
    for (int g = 0; g < 4; ++g) {
        #pragma unroll
        for (int ph = 0; ph < 9; ++ph) {
            const int j = 9 * g + ph;
            const int z = dlo - 4 + j;               // slice consumed by F(j)
            bar_lds_only();   // orders: H(j)->F(j), W(j+1)->H(j+1), bufs freed

            // F(j): issue LDS reads first
            const bool val = (z >= 0) && (z < DD);   // block-uniform
            float* shR = (j & 1) ? SH1 : SH0;
            float w0=0.f, w1=0.f, w2=0.f, w3=0.f, w4=0.f;
            if (val) {
                const float* pF = shR + (ty * TW + tx) * 5;
                w0 = pF[0]; w1 = pF[1]; w2 = pF[2]; w3 = pF[3]; w4 = pF[4];
            }

            // H(j+1): SW[(j+1)&1] -> SH[(j+1)&1]   (guard j+1 <= ITERS-1)
            if ((g < 3 || ph < 8) && hact) {
                const int zh = z + 1;
                if (zh >= 0 && zh < DD)
                    h_phase((j & 1) ? SW0 : SW1, (j & 1) ? SH0 : SH1);
            }

            // W(j+2): pf regs -> SW[(j+2)&1]; refill pf   (guard j+2 <= ITERS-1)
            if (g < 3 || ph < 7) {
                const int zw = z + 2;
                if (zw >= 0 && zw < DD) w_compute((j & 1) ? SW1 : SW0);
                w_load(z + 3);
            }

            // ring update + cc
            r0 += w0 - q0[ph]; q0[ph] = w0;
            r1 += w1 - q1[ph]; q1[ph] = w1;
            r2 += w2 - q2[ph]; q2[ph] = w2;
            r3 += w3 - q3[ph]; q3[ph] = w3;
            r4 += w4 - q4[ph]; q4[ph] = w4;

            if (j >= 8 && (dlo + j - 8) < DD) {   // last chunk overhangs to 167
                float cross = r4 - r0 * r1 * INV_WSUM;
                float iv    = r2 - r0 * r0 * INV_WSUM;
                float jv    = r3 - r1 * r1 * INV_WSUM;
                acc += cross * cross * __builtin_amdgcn_rcpf(iv * jv + EPS);
            }
        }
    }

    // ---- block reduction -> one atomic (cold path: full __syncthreads ok) ----
    #pragma unroll
    for (int off = 32; off > 0; off >>= 1) acc += __shfl_down(acc, off, 64);
    if ((tid & 63) == 0) wred[tid >> 6] = acc;
    __syncthreads();
    if (tid == 0) {
        float t = 0.f;
        #pragma unroll
        for (int k = 0; k < NTHR / 64; ++k) t += wred[k];
        atomicAdd(out, t * (-1.0f / (float)NVOX));
    }
}

extern "C" void kernel_launch(void* const* d_in, const int* in_sizes, int n_in,
                              void* d_out, int out_size, void* d_ws, size_t ws_size,
                              hipStream_t stream) {
    const float* I = (const float*)d_in[0];
    const float* J = (const float*)d_in[1];
    float* out = (float*)d_out;

    hipMemsetAsync(d_out, 0, sizeof(float), stream);  // harness re-poisons d_out

    dim3 blk(NTHR, 1, 1);
    dim3 grd(WW / TW, HH / TH, (DD + DCH - 1) / DCH); // 7 x 24 x 6 = 1008 blocks
    ncc_fused<<<grd, blk, 0, stream>>>(I, J, out);
}